// Round 11
// baseline (182.172 us; speedup 1.0000x reference)
//
#include <hip/hip_runtime.h>
#include <math.h>

#define PS    65
#define PP    68                 // patch pitch: rows 16B-aligned (272B)
#define NTH   320

// atan(t)*(4/pi) for t in [0,1], degree-9 odd minimax, |err|<=1.3e-5
#define C0  1.2730689f
#define C1 -0.4205505f
#define C2  0.2293627f
#define C3 -0.1083947f
#define C4  0.0265281f

// triangular pooling weight, compile-time
__host__ __device__ constexpr float triwc(int t) {
    float d = (float)t - 12.5f;
    d = d < 0.0f ? -d : d;
    return (13.0f - d) / 13.0f;
}

__global__ __launch_bounds__(NTH, 1) void sift_desc_kernel(
        const float* __restrict__ img, float* __restrict__ out) {
    const int s   = blockIdx.x;     // slice index in (B, C, 8, 8) row-major
    const int tid = threadIdx.x;

    // decode slice -> (b, c, tile_i, tile_j)
    const int b   = s / 192;        // C*8*8 = 192
    const int rem = s - b * 192;
    const int c   = rem >> 6;
    const int t2  = rem & 63;
    const int pi  = t2 >> 3;
    const int pj  = t2 & 7;
    const float* src = img + ((size_t)((b * 3 + c) * 520 + pi * 65)) * 520 + pj * 65;

    __shared__ __align__(16) float patch[PS * PP];  // 17.7 KB; aliased as fin later
    __shared__ __align__(16) float S[2080];         // W[y][j][k] = S[(4y+j)*8+k]
    __shared__ __align__(16) float gtab[PP];        // normalized gaussian * sqrt(0.5)
    __shared__ float redv[4];

    float* fin = patch;   // patch is dead after the fused pass (barrier-separated)

    // phase 0: gaussian + stage patch (pitch 68)
    if (tid < PS) {
        float d = (float)(tid - 32);
        gtab[tid] = expf(-(d * d) * (1.0f / 4225.0f));  // sigma=65/sqrt2 -> 2s^2=4225
    }
    for (int p = tid; p < PS * PS; p += NTH) {
        int y = p / 65;
        int x = p - y * 65;
        patch[y * PP + x] = src[y * 520 + x];
    }
    __syncthreads();

    // normalize gtab; fold sqrt(0.5) (the two 0.5 gradient factors, one per axis)
    if (tid < 64) {
        float v = gtab[tid] + ((tid == 0) ? gtab[64] : 0.0f);
        #pragma unroll
        for (int off = 32; off > 0; off >>= 1) v += __shfl_down(v, off);
        if (tid == 0) redv[0] = 0.70710678f / v;
    }
    __syncthreads();
    const float invZ = redv[0];
    if (tid < PS) gtab[tid] *= invZ;
    __syncthreads();

    // ---- fused pass: item = (row y, quarter q), tid = 4y+q. Strip-wise float4
    // prefetch (named bufs, ~2-strip lookahead; NO bulk arrays -> no spill).
    // 24 register accumulators; neighbor-window merge via shfl; 2 b128 stores.
    if (tid < 260) {
        const int y  = tid >> 2;
        const int q  = tid & 3;
        const int x0 = q << 4;
        const int rowb = y * PP;
        const int rowm = (y > 0  ? y - 1 : 0)  * PP;
        const int rowp = (y < 64 ? y + 1 : 64) * PP;
        const float gy_t = gtab[y];

        const float4* Crow = (const float4*)&patch[rowb + x0];
        const float4* Trow = (const float4*)&patch[rowm + x0];
        const float4* Brow = (const float4*)&patch[rowp + x0];
        const float4* Grow = (const float4*)&gtab[x0];

        // prefetch strips 0,1
        float4 C0v = Crow[0], T0v = Trow[0], B0v = Brow[0], G0v = Grow[0];
        float4 C1v = Crow[1], T1v = Trow[1], B1v = Brow[1], G1v = Grow[1];
        const float cm1 = patch[rowb + (q ? x0 - 1 : 0)];

        float accQ[8] = {0,0,0,0,0,0,0,0};   // window q   (all px,      t=i+6)
        float accB[8] = {0,0,0,0,0,0,0,0};   // window q-1 (px i=0..3,   t=i+22)
        float accP[8] = {0,0,0,0,0,0,0,0};   // window q+1 (px i=10..15, t=i-10)

        float prev = cm1, cur = C0v.x;

        auto PX = [&](float cn, float tp, float bt, float gxt,
                      float WA, float WB, float WP) {
            float G = cn - prev;                // 2*gx
            float H = bt - tp;                  // 2*gy
            float mag = sqrtf(fmaf(G, G, fmaf(H, H, 4e-10f))) * (gy_t * gxt);
            float Gx = G + 2e-10f;
            float ax = fabsf(Gx), ay = fabsf(H);
            float mn = fminf(ax, ay), mx = fmaxf(ax, ay);
            float t1 = mn * __builtin_amdgcn_rcpf(fmaxf(mx, 1e-35f));
            float ss = t1 * t1;
            float u9 = t1 * fmaf(ss, fmaf(ss, fmaf(ss, fmaf(ss, C4, C3), C2), C1), C0);
            float A  = (ay > ax) ? 2.0f - u9 : u9;
            A = (Gx < 0.0f) ? 4.0f - A : A;
            A = (H  < 0.0f) ? -A : A;
            float ob = A + 8.0f;                // in [4,12]
            float fl = truncf(ob);
            float fr = ob - fl;
            int b0 = ((int)fl) & 7;
            float w1 = fr * mag;
            float w0 = mag - w1;
            float sarr[8];
            #pragma unroll
            for (int k = 0; k < 8; ++k) {
                const int km1 = (k + 7) & 7;
                float sv = (b0 == k) ? w0 : 0.0f;
                sarr[k] = (b0 == km1) ? w1 : sv;
            }
            #pragma unroll
            for (int k = 0; k < 8; ++k) accQ[k] = fmaf(sarr[k], WA, accQ[k]);
            if (WB > 0.0f) {
                #pragma unroll
                for (int k = 0; k < 8; ++k) accB[k] = fmaf(sarr[k], WB, accB[k]);
            }
            if (WP > 0.0f) {
                #pragma unroll
                for (int k = 0; k < 8; ++k) accP[k] = fmaf(sarr[k], WP, accP[k]);
            }
            prev = cur; cur = cn;
        };

        // strip 0 (i=0..3), prefetch strip 2 first
        float4 C2v = Crow[2], T2v = Trow[2], B2v = Brow[2], G2v = Grow[2];
        PX(C0v.y, T0v.x, B0v.x, G0v.x, triwc(6),  triwc(22), 0.0f);
        PX(C0v.z, T0v.y, B0v.y, G0v.y, triwc(7),  triwc(23), 0.0f);
        PX(C0v.w, T0v.z, B0v.z, G0v.z, triwc(8),  triwc(24), 0.0f);
        PX(C1v.x, T0v.w, B0v.w, G0v.w, triwc(9),  triwc(25), 0.0f);
        // strip 1 (i=4..7), prefetch strip 3 first
        float4 C3v = Crow[3], T3v = Trow[3], B3v = Brow[3], G3v = Grow[3];
        PX(C1v.y, T1v.x, B1v.x, G1v.x, triwc(10), 0.0f, 0.0f);
        PX(C1v.z, T1v.y, B1v.y, G1v.y, triwc(11), 0.0f, 0.0f);
        PX(C1v.w, T1v.z, B1v.z, G1v.z, triwc(12), 0.0f, 0.0f);
        PX(C2v.x, T1v.w, B1v.w, G1v.w, triwc(13), 0.0f, 0.0f);
        // strip 2 (i=8..11), prefetch tail scalars first
        const float c16 = patch[rowb + x0 + 16];
        const float t16 = patch[rowm + x0 + 16];
        const float b16 = patch[rowp + x0 + 16];
        const float g16 = gtab[x0 + 16];
        PX(C2v.y, T2v.x, B2v.x, G2v.x, triwc(14), 0.0f, 0.0f);
        PX(C2v.z, T2v.y, B2v.y, G2v.y, triwc(15), 0.0f, 0.0f);
        PX(C2v.w, T2v.z, B2v.z, G2v.z, triwc(16), 0.0f, triwc(0));
        PX(C3v.x, T2v.w, B2v.w, G2v.w, triwc(17), 0.0f, triwc(1));
        // strip 3 (i=12..15)
        PX(C3v.y, T3v.x, B3v.x, G3v.x, triwc(18), 0.0f, triwc(2));
        PX(C3v.z, T3v.y, B3v.y, G3v.y, triwc(19), 0.0f, triwc(3));
        PX(C3v.w, T3v.z, B3v.z, G3v.z, triwc(20), 0.0f, triwc(4));
        PX(c16,   T3v.w, B3v.w, G3v.w, triwc(21), 0.0f, triwc(5));
        // 17th pixel x=64 (q=3 only): cnext clamps to itself (cn = c16 = cur)
        if (q == 3) {
            PX(c16, t16, b16, g16, triwc(22), 0.0f, 0.0f);
        }

        // merge neighbor windows via shfl (groups of 4 never straddle a wave)
        const float fB = (q < 3) ? 1.0f : 0.0f;
        const float fP = (q > 0) ? 1.0f : 0.0f;
        float wk0, wk1, wk2, wk3, wk4, wk5, wk6, wk7;
        {
            float w[8];
            #pragma unroll
            for (int k = 0; k < 8; ++k) {
                float nb = __shfl_down(accB[k], 1);   // from q+1: its window q
                float np = __shfl_up(accP[k], 1);     // from q-1: its window q
                w[k] = accQ[k] + fB * nb + fP * np;
            }
            wk0=w[0]; wk1=w[1]; wk2=w[2]; wk3=w[3];
            wk4=w[4]; wk5=w[5]; wk6=w[6]; wk7=w[7];
        }
        *(float4*)&S[tid * 8]     = make_float4(wk0, wk1, wk2, wk3);
        *(float4*)&S[tid * 8 + 4] = make_float4(wk4, wk5, wk6, wk7);
    }
    __syncthreads();

    // ---- row pass: bin = k*16 + ii*4 + j sums W[y][j][k] with triangular wy
    if (tid < 128) {
        const int k  = tid >> 4;
        const int ii = (tid >> 2) & 3;
        const int j  = tid & 3;
        float v = 0.0f;
        #pragma unroll
        for (int t = 0; t < 26; ++t) {
            const int y  = 16 * ii + t - 6;
            const int yc = (y < 0) ? 0 : ((y > 64) ? 64 : y);
            const float wy = (y == yc) ? triwc(t) : 0.0f;
            v = fmaf(wy, S[((yc << 2) + j) * 8 + k], v);
        }
        fin[tid] = v;   // fin aliases patch (dead), safe post-barrier
    }
    __syncthreads();

    // first L2 norm
    if (tid < 64) {
        float sq = fin[tid] * fin[tid] + fin[tid + 64] * fin[tid + 64];
        #pragma unroll
        for (int off = 32; off > 0; off >>= 1) sq += __shfl_down(sq, off);
        if (tid == 0) redv[1] = sq;
    }
    __syncthreads();
    float inv1 = 1.0f / fmaxf(sqrtf(redv[1]), 1e-12f);
    if (tid < 128) {
        fin[tid] = fminf(fin[tid] * inv1, 0.2f);   // non-negative; clip hi only
    }
    __syncthreads();

    // second L2 norm
    if (tid < 64) {
        float sq = fin[tid] * fin[tid] + fin[tid + 64] * fin[tid + 64];
        #pragma unroll
        for (int off = 32; off > 0; off >>= 1) sq += __shfl_down(sq, off);
        if (tid == 0) redv[2] = sq;
    }
    __syncthreads();
    float inv2 = 1.0f / fmaxf(sqrtf(redv[2]), 1e-12f);
    if (tid < 128) {
        out[(size_t)s * 128 + tid] = fin[tid] * inv2;
    }
}

extern "C" void kernel_launch(void* const* d_in, const int* in_sizes, int n_in,
                              void* d_out, int out_size, void* d_ws, size_t ws_size,
                              hipStream_t stream) {
    const float* img = (const float*)d_in[0];
    float* out = (float*)d_out;
    const int B = in_sizes[0] / (3 * 520 * 520);
    const int nslices = B * 192;
    sift_desc_kernel<<<nslices, NTH, 0, stream>>>(img, out);
}

// Round 12
// 114.818 us; speedup vs baseline: 1.5866x; 1.5866x over previous
//
#include <hip/hip_runtime.h>
#include <math.h>

#define PS     65
#define NPIX   (PS * PS)
#define PWP    75                 // PW pitch (odd: 11y mod 32 spreads banks, <=2-way)
#define NTH    256

// atan(t)*(4/pi) for t in [0,1], degree-9 odd minimax, |err|<=1.3e-5
#define C0  1.2730689f
#define C1 -0.4205505f
#define C2  0.2293627f
#define C3 -0.1083947f
#define C4  0.0265281f

#define QS  8388608.0f            // 2^23 fixed-point pack scale (cancels in L2 norms)

// triangular pooling weight, compile-time
__host__ __device__ constexpr float triwc(int t) {
    float d = (float)t - 12.5f;
    d = d < 0.0f ? -d : d;
    return (13.0f - d) / 13.0f;
}

__global__ __launch_bounds__(NTH) void sift_desc_kernel(
        const float* __restrict__ img, float* __restrict__ out) {
    const int s   = blockIdx.x;     // slice index in (B, C, 8, 8) row-major
    const int tid = threadIdx.x;

    // decode slice -> (b, c, tile_i, tile_j)
    const int b   = s / 192;        // C*8*8 = 192
    const int rem = s - b * 192;
    const int c   = rem >> 6;
    const int t2  = rem & 63;
    const int pi  = t2 >> 3;
    const int pj  = t2 & 7;
    const float* src = img + ((size_t)((b * 3 + c) * 520 + pi * 65)) * 520 + pj * 65;

    __shared__ __align__(16) float patch[NPIX];   // 16.9 KB; aliased as W after pass1
    __shared__ unsigned int PW[PS * PWP];         // 19.5 KB packed (w0,w1,b0)
    __shared__ float gtab[PS];
    __shared__ float fin[128];
    __shared__ float redv[2];

    float* S = patch;   // W[260][8]: S[(4y+j)*8+k]; patch dead after pass 1

    // phase 0: zero PW (pads must be 0), gaussian table, stage patch
    for (int k = tid; k < PS * PWP; k += NTH) PW[k] = 0u;
    if (tid < PS) {
        float d = (float)(tid - 32);
        gtab[tid] = expf(-(d * d) * (1.0f / 4225.0f));   // sigma=65/sqrt2 -> 2s^2=4225
    }
    for (int p = tid; p < NPIX; p += NTH) {
        int y = p / 65;
        int x = p - y * 65;
        patch[p] = src[y * 520 + x];
    }
    __syncthreads();

    // normalize gtab; fold sqrt(0.5) (the two 0.5 gradient factors)
    if (tid < 64) {
        float v = gtab[tid] + ((tid == 0) ? gtab[64] : 0.0f);
        #pragma unroll
        for (int off = 32; off > 0; off >>= 1) v += __shfl_down(v, off);
        if (tid == 0) redv[0] = 0.70710678f / v;
    }
    __syncthreads();
    const float invZ = redv[0];
    if (tid < PS) gtab[tid] *= invZ;
    __syncthreads();

    // ---- pass 1: per-pixel math ONCE; item e = (row y, x-quarter q), sliding window
    for (int e = tid; e < 260; e += NTH) {
        const int y  = e >> 2;
        const int q  = e & 3;
        const int x0 = q << 4;

        const int rowb = y * 65;
        const int rowm = (y > 0  ? y - 1 : 0)  * 65;
        const int rowp = (y < 64 ? y + 1 : 64) * 65;
        const float gy_t = gtab[y];
        const int pwb = y * PWP + 6 + x0;          // store at col x+6

        float cprev = patch[rowb + ((q == 0) ? 0 : x0 - 1)];
        float ccur  = patch[rowb + x0];

#define PX1(XEXPR, CNEXT_EXPR, PWIDX)                                          \
        {                                                                      \
            const int x = (XEXPR);                                             \
            float cnext = (CNEXT_EXPR);                                        \
            float top = patch[rowm + x];                                       \
            float bot = patch[rowp + x];                                       \
            float G = cnext - cprev;          /* 2*gx */                       \
            float H = bot - top;              /* 2*gy */                       \
            float mag = sqrtf(fmaf(G, G, fmaf(H, H, 4e-10f))) * (gy_t * gtab[x]); \
            float Gx = G + 2e-10f;                                             \
            float ax = fabsf(Gx), ay = fabsf(H);                               \
            float mn = fminf(ax, ay), mx = fmaxf(ax, ay);                      \
            float t1 = mn * __builtin_amdgcn_rcpf(fmaxf(mx, 1e-35f));          \
            float ss = t1 * t1;                                                \
            float u9 = t1 * fmaf(ss, fmaf(ss, fmaf(ss, fmaf(ss, C4, C3), C2), C1), C0); \
            float A  = (ay > ax) ? 2.0f - u9 : u9;                             \
            A = (Gx < 0.0f) ? 4.0f - A : A;                                    \
            A = (H  < 0.0f) ? -A : A;                                          \
            float ob = A + 8.0f;              /* in [4,12] */                  \
            float fl = truncf(ob);                                             \
            float fr = ob - fl;                                                \
            int b0 = ((int)fl) & 7;                                            \
            float w1 = fr * mag;                                               \
            float w0 = mag - w1;                                               \
            unsigned uq0 = (unsigned)fminf(w0 * QS, 16383.0f);                 \
            unsigned uq1 = (unsigned)fminf(w1 * QS, 16383.0f);                 \
            PW[PWIDX] = uq0 | (uq1 << 14) | ((unsigned)b0 << 28);              \
            cprev = ccur; ccur = cnext;                                        \
        }

        #pragma unroll
        for (int i = 0; i < 16; ++i) {
            PX1(x0 + i, patch[rowb + x + 1], pwb + i)
        }
        if (q == 3) {
            PX1(64, ccur, pwb + 16)     // right neighbor clamps to itself
        }
#undef PX1
    }
    __syncthreads();

    // ---- pass 2: item e = (row y, window j). 8 REGISTER accumulators, select
    // chain per pixel (R3-style, proven 97% issue); no LDS RMW anywhere.
    for (int e = tid; e < 260; e += NTH) {
        const int y = e >> 2;
        const int j = e & 3;
        const unsigned int* pwrow = &PW[y * PWP + (j << 4)];  // col 16j+t, t=0..25

        float a0 = 0.f, a1 = 0.f, a2 = 0.f, a3 = 0.f;
        float a4 = 0.f, a5 = 0.f, a6 = 0.f, a7 = 0.f;

        #pragma unroll
        for (int t = 0; t < 26; ++t) {
            const float wq = triwc(t) * (1.0f / QS);   // compile-time
            unsigned u = pwrow[t];
            float q0f = (float)(u & 0x3FFFu);
            float q1f = (float)((u >> 14) & 0x3FFFu);
            int   b0  = (int)(u >> 28);
            float v;
            v = (b0 == 0) ? q0f : 0.f; v = (b0 == 7) ? q1f : v; a0 = fmaf(v, wq, a0);
            v = (b0 == 1) ? q0f : 0.f; v = (b0 == 0) ? q1f : v; a1 = fmaf(v, wq, a1);
            v = (b0 == 2) ? q0f : 0.f; v = (b0 == 1) ? q1f : v; a2 = fmaf(v, wq, a2);
            v = (b0 == 3) ? q0f : 0.f; v = (b0 == 2) ? q1f : v; a3 = fmaf(v, wq, a3);
            v = (b0 == 4) ? q0f : 0.f; v = (b0 == 3) ? q1f : v; a4 = fmaf(v, wq, a4);
            v = (b0 == 5) ? q0f : 0.f; v = (b0 == 4) ? q1f : v; a5 = fmaf(v, wq, a5);
            v = (b0 == 6) ? q0f : 0.f; v = (b0 == 5) ? q1f : v; a6 = fmaf(v, wq, a6);
            v = (b0 == 7) ? q0f : 0.f; v = (b0 == 6) ? q1f : v; a7 = fmaf(v, wq, a7);
        }

        // W[e][k], written once (aliases dead patch)
        *(float4*)&S[e * 8]     = make_float4(a0, a1, a2, a3);
        *(float4*)&S[e * 8 + 4] = make_float4(a4, a5, a6, a7);
    }
    __syncthreads();

    // ---- row pass: bin = k*16 + ii*4 + j sums W[4y+j][k] with triangular wy
    if (tid < 128) {
        const int k  = tid >> 4;
        const int ii = (tid >> 2) & 3;
        const int j  = tid & 3;
        float v = 0.0f;
        #pragma unroll
        for (int t = 0; t < 26; ++t) {
            const int y  = 16 * ii + t - 6;
            const int yc = (y < 0) ? 0 : ((y > 64) ? 64 : y);
            const float wy = (y == yc) ? triwc(t) : 0.0f;
            v = fmaf(wy, S[((yc << 2) + j) * 8 + k], v);
        }
        fin[tid] = v;
    }
    __syncthreads();

    // first L2 norm
    if (tid < 64) {
        float sq = fin[tid] * fin[tid] + fin[tid + 64] * fin[tid + 64];
        #pragma unroll
        for (int off = 32; off > 0; off >>= 1) sq += __shfl_down(sq, off);
        if (tid == 0) redv[0] = sq;
    }
    __syncthreads();
    float inv1 = 1.0f / fmaxf(sqrtf(redv[0]), 1e-12f);
    if (tid < 128) {
        fin[tid] = fminf(fin[tid] * inv1, 0.2f);   // non-negative; clip hi only
    }
    __syncthreads();

    // second L2 norm
    if (tid < 64) {
        float sq = fin[tid] * fin[tid] + fin[tid + 64] * fin[tid + 64];
        #pragma unroll
        for (int off = 32; off > 0; off >>= 1) sq += __shfl_down(sq, off);
        if (tid == 0) redv[1] = sq;
    }
    __syncthreads();
    float inv2 = 1.0f / fmaxf(sqrtf(redv[1]), 1e-12f);
    if (tid < 128) {
        out[(size_t)s * 128 + tid] = fin[tid] * inv2;
    }
}

extern "C" void kernel_launch(void* const* d_in, const int* in_sizes, int n_in,
                              void* d_out, int out_size, void* d_ws, size_t ws_size,
                              hipStream_t stream) {
    const float* img = (const float*)d_in[0];
    float* out = (float*)d_out;
    const int B = in_sizes[0] / (3 * 520 * 520);
    const int nslices = B * 192;
    sift_desc_kernel<<<nslices, NTH, 0, stream>>>(img, out);
}

// Round 13
// 90.559 us; speedup vs baseline: 2.0116x; 1.2679x over previous
//
#include <hip/hip_runtime.h>
#include <math.h>

#define PS    65
#define PWP   74                // PW pitch
#define SPIT  36                // ring-row pitch: 4 windows x 9 slots
#define SROWS 77                // ring rows: y+6, y in [-6,70]
#define SSZ   (SROWS * SPIT)    // 2772 floats
#define NTH   256
#define QS    1024.0f           // 14-bit pack scale (global scale cancels in L2 norms)

// atan(t)*(4/pi) for t in [0,1], degree-9 odd minimax, |err|<=1.3e-5
#define C0  1.2730689f
#define C1 -0.4205505f
#define C2  0.2293627f
#define C3 -0.1083947f
#define C4  0.0265281f

// triangular pooling weight, compile-time
__host__ __device__ constexpr float triwc(int t) {
    float d = (float)t - 12.5f;
    d = d < 0.0f ? -d : d;
    return (13.0f - d) / 13.0f;
}

__global__ __launch_bounds__(NTH) void sift_desc_kernel(
        const float* __restrict__ img, float* __restrict__ out) {
    const int s   = blockIdx.x;     // slice index in (B, C, 8, 8) row-major
    const int tid = threadIdx.x;

    // decode slice -> (b, c, tile_i, tile_j)
    const int b   = s / 192;        // C*8*8 = 192
    const int rem = s - b * 192;
    const int c   = rem >> 6;
    const int t2  = rem & 63;
    const int pi  = t2 >> 3;
    const int pj  = t2 & 7;
    const float* src = img + ((size_t)((b * 3 + c) * 520 + pi * 65)) * 520 + pj * 65;

    __shared__ unsigned int PW[PS * PWP];   // 19.2 KB packed (w0,w1,b0), pads zero
    __shared__ float S[SSZ];                // 11.1 KB rings
    __shared__ float gtab[PS];              // UNNORMALIZED gaussian (scale cancels)
    __shared__ float fin[128];
    __shared__ float redv[2];

    // phase 0: gaussian; zero PW pad cols (0..5, 71..73); zero rings
    if (tid < PS) {
        float d = (float)(tid - 32);
        gtab[tid] = expf(-(d * d) * (1.0f / 4225.0f));  // sigma=65/sqrt2 -> 2s^2=4225
    }
    for (int k = tid; k < 585; k += NTH) {              // 65 rows x 9 pad cols
        int r = k / 9, cc = k - 9 * r;
        int col = (cc < 6) ? cc : cc + 65;              // 6..8 -> 71..73
        PW[r * PWP + col] = 0u;
    }
    for (int k = tid; k < SSZ; k += NTH) S[k] = 0.0f;
    __syncthreads();

    // ---- pass 1: per-pixel math ONCE, reading tile DIRECTLY from global
    // (L1/L2-served; immediate-offset loads). item e = (row y, x-quarter q).
    for (int e = tid; e < 260; e += NTH) {
        const int y  = e >> 2;
        const int q  = e & 3;
        const int x0 = q << 4;

        const float* pc = src + y * 520 + x0;
        const float* pm = src + (y > 0  ? y - 1 : 0)  * 520 + x0;
        const float* pp = src + (y < 64 ? y + 1 : 64) * 520 + x0;
        const float gy_t = gtab[y];
        const int pwb = y * PWP + 6 + x0;          // store at col x+6

        float cprev = (q == 0) ? pc[0] : pc[-1];
        float ccur  = pc[0];

#define PX1(CNEXT_EXPR, TOP, BOT, GXT, PWIDX)                                  \
        {                                                                      \
            float cnext = (CNEXT_EXPR);                                        \
            float G = cnext - cprev;          /* 2*gx */                       \
            float H = (BOT) - (TOP);          /* 2*gy */                       \
            float mag = sqrtf(fmaf(G, G, fmaf(H, H, 4e-10f))) * (gy_t * (GXT)); \
            float Gx = G + 2e-10f;                                             \
            float ax = fabsf(Gx), ay = fabsf(H);                               \
            float mn = fminf(ax, ay), mx = fmaxf(ax, ay);                      \
            float t1 = mn * __builtin_amdgcn_rcpf(fmaxf(mx, 1e-35f));          \
            float ss = t1 * t1;                                                \
            float u9 = t1 * fmaf(ss, fmaf(ss, fmaf(ss, fmaf(ss, C4, C3), C2), C1), C0); \
            float A  = (ay > ax) ? 2.0f - u9 : u9;                             \
            A = (Gx < 0.0f) ? 4.0f - A : A;                                    \
            A = (H  < 0.0f) ? -A : A;                                          \
            float ob = A + 8.0f;              /* in [4,12] */                  \
            float fl = truncf(ob);                                             \
            float fr = ob - fl;                                                \
            int b0 = ((int)fl) & 7;                                            \
            float w1 = fr * mag;                                               \
            float w0 = mag - w1;                                               \
            unsigned uq0 = (unsigned)fminf(w0 * QS, 16383.0f);                 \
            unsigned uq1 = (unsigned)fminf(w1 * QS, 16383.0f);                 \
            PW[PWIDX] = uq0 | (uq1 << 14) | ((unsigned)b0 << 28);              \
            cprev = ccur; ccur = cnext;                                        \
        }

        #pragma unroll
        for (int i = 0; i < 16; ++i) {
            PX1(pc[i + 1], pm[i], pp[i], gtab[x0 + i], pwb + i)
        }
        if (q == 3) {   // x=64: right neighbor clamps to itself (cnext = ccur)
            PX1(ccur, pm[16], pp[16], gtab[64], pwb + 16)
        }
#undef PX1
    }
    __syncthreads();

    // ---- pass 2: item e = (row y, window j). Thread exclusively owns a 9-slot
    // ring S[(y+6)*SPIT + j*9 + (0..8)]; b0,b0+1 adjacent -> ds_read2/write2.
    for (int e = tid; e < 260; e += NTH) {
        const int y = e >> 2;
        const int j = e & 3;
        const unsigned int* pwrow = &PW[y * PWP + (j << 4)];  // col 16j+t, t=0..25
        float* ring = &S[(y + 6) * SPIT + j * 9];

        #pragma unroll
        for (int t = 0; t < 26; ++t) {
            const float wq = triwc(t);                 // compile-time
            unsigned u = pwrow[t];
            float q0f = (float)(u & 0x3FFFu);
            float q1f = (float)((u >> 14) & 0x3FFFu);
            int   b0  = (int)(u >> 28);
            ring[b0]     = fmaf(q0f, wq, ring[b0]);
            ring[b0 + 1] = fmaf(q1f, wq, ring[b0 + 1]);
        }
    }
    __syncthreads();

    // fold ring slot 8 into slot 0 (bin-0 wrap)
    for (int k = tid; k < SROWS * 4; k += NTH) {
        const int r = k >> 2;
        const int j = k & 3;
        const int o = r * SPIT + j * 9;
        S[o] += S[o + 8];
    }
    __syncthreads();

    // ---- row pass: bin = k*16 + ii*4 + j sums ring slot k over t=0..25
    // (ring row = 16*ii + t; pad rows are zero -> no bounds checks)
    if (tid < 128) {
        const int k  = tid >> 4;
        const int ii = (tid >> 2) & 3;
        const int j  = tid & 3;
        float v = 0.0f;
        #pragma unroll
        for (int t = 0; t < 26; ++t) {
            v = fmaf(triwc(t), S[(16 * ii + t) * SPIT + j * 9 + k], v);
        }
        fin[tid] = v;
    }
    __syncthreads();

    // first L2 norm
    if (tid < 64) {
        float sq = fin[tid] * fin[tid] + fin[tid + 64] * fin[tid + 64];
        #pragma unroll
        for (int off = 32; off > 0; off >>= 1) sq += __shfl_down(sq, off);
        if (tid == 0) redv[0] = sq;
    }
    __syncthreads();
    float inv1 = 1.0f / fmaxf(sqrtf(redv[0]), 1e-12f);
    if (tid < 128) {
        fin[tid] = fminf(fin[tid] * inv1, 0.2f);   // non-negative; clip hi only
    }
    __syncthreads();

    // second L2 norm
    if (tid < 64) {
        float sq = fin[tid] * fin[tid] + fin[tid + 64] * fin[tid + 64];
        #pragma unroll
        for (int off = 32; off > 0; off >>= 1) sq += __shfl_down(sq, off);
        if (tid == 0) redv[1] = sq;
    }
    __syncthreads();
    float inv2 = 1.0f / fmaxf(sqrtf(redv[1]), 1e-12f);
    if (tid < 128) {
        out[(size_t)s * 128 + tid] = fin[tid] * inv2;
    }
}

extern "C" void kernel_launch(void* const* d_in, const int* in_sizes, int n_in,
                              void* d_out, int out_size, void* d_ws, size_t ws_size,
                              hipStream_t stream) {
    const float* img = (const float*)d_in[0];
    float* out = (float*)d_out;
    const int B = in_sizes[0] / (3 * 520 * 520);
    const int nslices = B * 192;
    sift_desc_kernel<<<nslices, NTH, 0, stream>>>(img, out);
}